// Round 1
// baseline (183.051 us; speedup 1.0000x reference)
//
#include <hip/hip_runtime.h>

// R11: wave-specialized anti-phase producer/consumer LSTM.
// B=4096, L=256, H=32, D=2. 256 WGs x 512 threads, 16 batches/WG split into
// two independent 8-batch streams: waves 0-3 own stream A (batches 0-7),
// waves 4-7 own stream B (batches 8-15). Each stream alternates
//   MEM  phase: ds_read hfrag -> 8 MFMAs (4 gate quads x 2 unit-halves,
//               B cols duplicated across the 16-wide tile) -> gates in regs
//   CELL phase: trans-heavy cell update -> h write
// with one __syncthreads between phases. The groups run in OPPOSITE phases,
// so each SIMD always has one mem/MFMA wave + one transcendental wave:
// ds_read latency and MFMA issue of one stream hide under the other's
// quarter-rate exp2/rcp burst (the previous kernel's 8 lockstep waves
// serialized these phases -> 820 cyc/step).
// Head logits are FREE: Wo^T rows embedded at tile(0,0) rows 1,2 (rows !=0
// mod 4 are never consumed as gates), extracted from acc regs 1,2 in MEM.
// Gate extraction happens after the barrier (MFMA latency hidden).
// 511 half-step intervals + peel + tail; post-phase unchanged from R10.

typedef __attribute__((ext_vector_type(8))) short bf16x8;
typedef __attribute__((ext_vector_type(4))) float f32x4;

#define LOG2E 1.4426950408889634f
#define LN2   0.6931471805599453f

__device__ __forceinline__ float fexp2(float x) { return __builtin_amdgcn_exp2f(x); }
__device__ __forceinline__ float flog2(float x) { return __builtin_amdgcn_logf(x); }
__device__ __forceinline__ float frcp(float x)  { return __builtin_amdgcn_rcpf(x); }

__device__ __forceinline__ float fsig(float x)   { return frcp(1.f + fexp2(-LOG2E * x)); }
__device__ __forceinline__ float ftanh_(float x) { return 1.f - 2.f * frcp(fexp2(2.f * LOG2E * x) + 1.f); }
__device__ __forceinline__ float felu(float x)   { return x > 0.f ? x : fexp2(LOG2E * x) - 1.f; }

__device__ __forceinline__ unsigned short f2bf(float f) {   // RNE f32->bf16
    unsigned u = __builtin_bit_cast(unsigned, f);
    u = (u + 0x7FFFu + ((u >> 16) & 1u)) >> 16;
    return (unsigned short)u;
}

constexpr int Bsz = 4096;

__global__ __launch_bounds__(512, 2) void lstm_r11(
    const int*   __restrict__ x,    // [B, 256]
    const float* __restrict__ Wi,   // [2, 128]
    const float* __restrict__ Wh,   // [32, 128]
    const float* __restrict__ bh,   // [128]
    const float* __restrict__ Wo,   // [32, 2]
    const float* __restrict__ bo,   // [2]
    float*       __restrict__ out)  // [B]
{
    const int tid  = threadIdx.x;
    const int w    = tid >> 6;      // wave 0..7
    const int lane = tid & 63;
    const int m    = lane & 15;     // MFMA column
    const int oct  = lane >> 4;
    const int rot  = w & 3;         // gate-row rotation within group
    const int grp  = w >> 2;        // stream group: 0 = batches 0-7, 1 = 8-15
    const int mlo  = m & 7;         // batch within stream
    const int mhi  = m >> 3;        // unit half this lane extracts
    const int b0   = blockIdx.x * 16;

    __shared__ char   spinT[16][260];     // [batch][t] bytes, padded row
    __shared__ float2 Sbuf[256][16];      // raw logits (S0,S1) per (t,batch)
    __shared__ short  hbuf[2][8][40];     // per-stream h, row stride 80 B
    __shared__ float  red[8][16];

    // ---- stage spins: 512 threads x 8 ints ----
    {
        const int bl = tid >> 5;
        const int c8 = (tid & 31) * 8;
        const int4* src = reinterpret_cast<const int4*>(x + (b0 + bl) * 256 + c8);
        const int4 v0 = src[0], v1 = src[1];
        const int p0 = (v0.x & 1) | ((v0.y & 1) << 8) | ((v0.z & 1) << 16) | ((v0.w & 1) << 24);
        const int p1 = (v1.x & 1) | ((v1.y & 1) << 8) | ((v1.z & 1) << 16) | ((v1.w & 1) << 24);
        *reinterpret_cast<int*>(&spinT[bl][c8])     = p0;
        *reinterpret_cast<int*>(&spinT[bl][c8 + 4]) = p1;
    }

    // ---- weight A-frags: 8 tiles (gate q, unit-half hh), rows rotated by
    // rot; Wo^T head rows embedded at tile(0,0) rows 1,2 (redundant slots).
    bf16x8 wfrag[4][2];
#pragma unroll
    for (int q = 0; q < 4; ++q) {
        const float gs = (q == 2) ? 2.f * LOG2E : -LOG2E;
#pragma unroll
        for (int hh = 0; hh < 2; ++hh) {
            const int colg = 32 * q + 16 * hh + ((m + rot) & 15);
#pragma unroll
            for (int j = 0; j < 8; ++j) {
                float v = gs * Wh[(oct * 8 + j) * 128 + colg];
                if (q == 0 && hh == 0 && m == 1) v = Wo[(oct * 8 + j) * 2 + 0];
                if (q == 0 && hh == 0 && m == 2) v = Wo[(oct * 8 + j) * 2 + 1];
                wfrag[q][hh][j] = (short)f2bf(v);
            }
        }
    }

    // ---- this lane's cell + scaled biases ----
    const int ucell = 4 * oct + rot + 16 * mhi;
    float bv0[4], bvd[4];
#pragma unroll
    for (int q = 0; q < 4; ++q) {
        const float gs = (q == 2) ? 2.f * LOG2E : -LOG2E;
        const int c0 = 32 * q + ucell;
        bv0[q] = gs * (bh[c0] + Wi[c0]);
        bvd[q] = gs * (Wi[128 + c0] - Wi[c0]);
    }
    const float bo0 = bo[0], bo1 = bo[1];

    // ---- peel t=0: input zeros, h=c=0 -> gates = bh ----
    float c = fsig(bh[ucell]) * ftanh_(bh[64 + ucell]);
    hbuf[grp][mlo][ucell] = (short)f2bf(fsig(bh[96 + ucell]) * ftanh_(c));
    __syncthreads();

    const int grpS = __builtin_amdgcn_readfirstlane(grp);
    const int rotS = __builtin_amdgcn_readfirstlane(rot);
    const f32x4 zero4 = { 0.f, 0.f, 0.f, 0.f };
    f32x4 accq[4][2];                 // gates of next cell, live across barrier
    int spn = 0;                      // prefetched spin byte

    const short* hrd = &hbuf[grp][mlo][8 * oct];   // b128 frag read (broadcast m/m+8)
    short*       hwr = &hbuf[grp][mlo][ucell];     // b16 scatter write
    const char*  srd = &spinT[grp * 8 + mlo][0];

    // MEM(tr): read h(tr), 8 MFMAs -> gates(tr+1) in accq; prefetch spin(tr);
    // head logits S(tr) from tile(0,0) regs 1,2, written round-robin by rot.
    auto MEM = [&](const int tr) {
        const bf16x8 hfrag = *reinterpret_cast<const bf16x8*>(hrd);
        spn = (int)srd[tr];
#pragma unroll
        for (int q = 0; q < 4; ++q)
#pragma unroll
            for (int hh = 0; hh < 2; ++hh)
                accq[q][hh] = __builtin_amdgcn_mfma_f32_16x16x32_bf16(
                    wfrag[q][hh], hfrag, zero4, 0, 0, 0);
        if (rotS == (tr & 3)) {
            if (oct == 0 && m < 8)
                Sbuf[tr][grp * 8 + m] = make_float2(accq[0][0][1], accq[0][0][2]);
        }
    };

    // CELL: bias + extract gates (reg0 of this lane's half), cell update,
    // write h. Combined-rcp form, 7 transcendentals.
    auto CELL = [&]() {
        const float spf = (float)spn;
        const float a0 = fmaf(spf, bvd[0], bv0[0]) + (mhi ? accq[0][1][0] : accq[0][0][0]);
        const float a1 = fmaf(spf, bvd[1], bv0[1]) + (mhi ? accq[1][1][0] : accq[1][0][0]);
        const float a2 = fmaf(spf, bvd[2], bv0[2]) + (mhi ? accq[2][1][0] : accq[2][0][0]);
        const float a3 = fmaf(spf, bvd[3], bv0[3]) + (mhi ? accq[3][1][0] : accq[3][0][0]);
        const float ei = fexp2(a0), ef = fexp2(a1);
        const float eg = fexp2(a2), eo = fexp2(a3);
        const float P = (1.f + ei) * (1.f + eg);
        const float Q = 1.f + ef;
        const float R = frcp(P * Q);
        const float gf  = P * R;                 // 1/(1+ef)
        const float igt = (eg - 1.f) * Q * R;    // sig(i)*tanh(g)
        c = fmaf(gf, c, igt);
        const float ec = fexp2(2.f * LOG2E * c);
        const float h  = (ec - 1.f) * frcp((1.f + eo) * (1.f + ec));
        *hwr = (short)f2bf(h);
    };

    // Anti-phase main loop: G0 does MEM in even intervals / CELL in odd;
    // G1 the opposite (prologue MEM(0) offsets it). Barriers at uniform
    // program points; each group only syncs against itself (disjoint LDS),
    // the shared barrier just locks the two groups anti-phase.
    if (grpS != 0) MEM(0);
    for (int j = 0; j < 255; ++j) {
        if (grpS == 0) MEM(j); else CELL();
        __syncthreads();
        if (grpS == 0) CELL(); else MEM(j + 1);
        __syncthreads();
    }
    // tail: S_A(255) (stream B got S_B(255) from its in-loop MEM(255))
    if (grpS == 0 && rotS == 0) {
        const bf16x8 hfrag = *reinterpret_cast<const bf16x8*>(hrd);
        const f32x4 hs = __builtin_amdgcn_mfma_f32_16x16x32_bf16(
            wfrag[0][0], hfrag, zero4, 0, 0, 0);
        if (oct == 0 && m < 8) Sbuf[255][m] = make_float2(hs[1], hs[2]);
    }
    __syncthreads();

    // ---- post phase: ELU + log-softmax + sum over t, 32 time-chunks ----
    float lp = 0.f;
    {
        const int t0 = (w * 4 + oct) * 8;
#pragma unroll
        for (int i = 0; i < 8; ++i) {
            const int t = t0 + i;
            const float2 sv = Sbuf[t][m];
            const int sp = spinT[m][t];
            const float o0 = felu(sv.x + bo0);
            const float o1 = felu(sv.y + bo1);
            const float mx = fmaxf(o0, o1), mn = fminf(o0, o1);
            const float lse = mx + LN2 * flog2(1.f + fexp2(LOG2E * (mn - mx)));
            lp += (sp ? o1 : o0) - lse;
        }
    }
    lp += __shfl_xor(lp, 16, 64);   // reduce over oct
    lp += __shfl_xor(lp, 32, 64);
    if (lane < 16) red[w][lane] = lp;
    __syncthreads();
    if (tid < 16) {
        float s = 0.f;
#pragma unroll
        for (int ww = 0; ww < 8; ++ww) s += red[ww][tid];
        out[b0 + tid] = 0.5f * s;
    }
}

extern "C" void kernel_launch(void* const* d_in, const int* in_sizes, int n_in,
                              void* d_out, int out_size, void* d_ws, size_t ws_size,
                              hipStream_t stream) {
    const int*   x  = (const int*)d_in[0];
    const float* Wi = (const float*)d_in[1];
    const float* Wh = (const float*)d_in[2];
    const float* bh = (const float*)d_in[3];
    const float* Wo = (const float*)d_in[4];
    const float* bo = (const float*)d_in[5];
    float* out = (float*)d_out;

    lstm_r11<<<dim3(Bsz / 16), dim3(512), 0, stream>>>(x, Wi, Wh, bh, Wo, bo, out);
}

// Round 2
// 134.507 us; speedup vs baseline: 1.3609x; 1.3609x over previous
//
#include <hip/hip_runtime.h>

// R12: decoupled dual-workgroup LSTM. B=4096, L=256, H=32, D=2.
// 512 WGs x 256 threads (4 waves), 8 batches/WG, 2 WGs per CU (LDS-capped).
// R11 post-mortem: intra-WG anti-phase CANNOT work — one barrier per WG
// serializes MEM+CELL latencies (1270 cyc/step). Decoupling needs separate
// WGs with separate barriers: each SIMD hosts 1 wave from each of 2
// INDEPENDENT WGs, so one WG's ds_read/MFMA/trans latency hides under the
// other's issue. Issue cost is unchanged vs R10 (4 MFMAs/wave):
//  - 4 waves = rotations 0..3; unit-half moves into acc regs: A-tile row
//    4a+r (r in {0,1}) carries gate col 32q+16r+4a+rot; lane (m,oct)
//    extracts reg r = m>>3 (1 cndmask per gate).
//  - rows r in {2,3} of the q=0 tile hold Wo cols 0,1 -> head logits free
//    in acc[0][2..3] (any oct), stored round-robin by wave (t-1)&3.
//  - B-frag cols = 8 batches duplicated (cols m and m+8 same batch).
// Main loop structure (2-step unroll, spin pair prefetch, one barrier per
// step, combined-rcp cell, post-loop ELU/log-softmax) carried from R10.
// Dynamic LDS pad (36 KB) caps residency at exactly 2 WGs/CU; grid 512 =
// total slots -> uniform 2/CU, no straggler CU.

typedef __attribute__((ext_vector_type(8))) short bf16x8;
typedef __attribute__((ext_vector_type(4))) float f32x4;

#define LOG2E 1.4426950408889634f
#define LN2   0.6931471805599453f

__device__ __forceinline__ float fexp2(float x) { return __builtin_amdgcn_exp2f(x); }
__device__ __forceinline__ float flog2(float x) { return __builtin_amdgcn_logf(x); }
__device__ __forceinline__ float frcp(float x)  { return __builtin_amdgcn_rcpf(x); }

__device__ __forceinline__ float fsig(float x)   { return frcp(1.f + fexp2(-LOG2E * x)); }
__device__ __forceinline__ float ftanh_(float x) { return 1.f - 2.f * frcp(fexp2(2.f * LOG2E * x) + 1.f); }
__device__ __forceinline__ float felu(float x)   { return x > 0.f ? x : fexp2(LOG2E * x) - 1.f; }

__device__ __forceinline__ unsigned short f2bf(float f) {   // RNE f32->bf16
    unsigned u = __builtin_bit_cast(unsigned, f);
    u = (u + 0x7FFFu + ((u >> 16) & 1u)) >> 16;
    return (unsigned short)u;
}

constexpr int Bsz = 4096;

__global__ __launch_bounds__(256, 2) void lstm_r12(
    const int*   __restrict__ x,    // [B, 256]
    const float* __restrict__ Wi,   // [2, 128]
    const float* __restrict__ Wh,   // [32, 128]
    const float* __restrict__ bh,   // [128]
    const float* __restrict__ Wo,   // [32, 2]
    const float* __restrict__ bo,   // [2]
    float*       __restrict__ out)  // [B]
{
    const int tid  = threadIdx.x;
    const int w    = tid >> 6;      // wave 0..3 == rotation
    const int lane = tid & 63;
    const int m    = lane & 15;     // MFMA column
    const int oct  = lane >> 4;
    const int rot  = w;
    const int mb   = m & 7;         // batch within WG
    const int hi   = m >> 3;        // unit half -> acc reg index
    const int b0   = blockIdx.x * 8;

    __shared__ char   spinT[8][260];      // [batch][t] bytes, padded row
    __shared__ float2 Sbuf[256][8];       // raw logits (S0,S1) per (t,batch)
    __shared__ short  hbuf[2][8][40];     // h dbuf, row stride 80 B (16B aligned)
    __shared__ float  red[4][8];

    // ---- stage spins: 256 threads x 8 ints ----
    {
        const int bl = tid >> 5;          // 0..7
        const int c8 = (tid & 31) * 8;
        const int4* src = reinterpret_cast<const int4*>(x + (b0 + bl) * 256 + c8);
        const int4 v0 = src[0], v1 = src[1];
        const int p0 = (v0.x & 1) | ((v0.y & 1) << 8) | ((v0.z & 1) << 16) | ((v0.w & 1) << 24);
        const int p1 = (v1.x & 1) | ((v1.y & 1) << 8) | ((v1.z & 1) << 16) | ((v1.w & 1) << 24);
        *reinterpret_cast<int*>(&spinT[bl][c8])     = p0;
        *reinterpret_cast<int*>(&spinT[bl][c8 + 4]) = p1;
    }

    // ---- weight A-frags: tile q row 4a+r (r=m&3, a=m>>2):
    //   r in {0,1}: gate col 32q + 16r + 4a + rot (scaled)
    //   r in {2,3}, q==0: Wo col r-2 (raw) -> free head logits
    bf16x8 wfrag[4];
#pragma unroll
    for (int q = 0; q < 4; ++q) {
        const float gs = (q == 2) ? 2.f * LOG2E : -LOG2E;
        const int r = m & 3, a = m >> 2;
#pragma unroll
        for (int j = 0; j < 8; ++j) {
            float v = 0.f;
            if (r < 2)          v = gs * Wh[(oct * 8 + j) * 128 + (32 * q + 16 * r + 4 * a + rot)];
            else if (q == 0)    v = Wo[(oct * 8 + j) * 2 + (r - 2)];
            wfrag[q][j] = (short)f2bf(v);
        }
    }

    // ---- this lane's cell + scaled biases ----
    const int ucell = 4 * oct + rot + 16 * hi;
    float bv0[4], bvd[4];
#pragma unroll
    for (int q = 0; q < 4; ++q) {
        const float gs = (q == 2) ? 2.f * LOG2E : -LOG2E;
        const int c0 = 32 * q + ucell;
        bv0[q] = gs * (bh[c0] + Wi[c0]);
        bvd[q] = gs * (Wi[128 + c0] - Wi[c0]);
    }
    const float bo0 = bo[0], bo1 = bo[1];

    // ---- peel t=0: input zeros, h=c=0 -> gates = bh ----
    float c = fsig(bh[ucell]) * ftanh_(bh[64 + ucell]);
    hbuf[0][mb][ucell] = (short)f2bf(fsig(bh[96 + ucell]) * ftanh_(c));
    __syncthreads();

    const int rotS = __builtin_amdgcn_readfirstlane(rot);
    const f32x4 zero4 = { 0.f, 0.f, 0.f, 0.f };

    const short* hrd = &hbuf[0][mb][8 * oct];   // base; rb offset added per call
    const int    hstride = 8 * 40;              // shorts between dbuf planes

    // one step; rb/wb compile-time at each call site -> static addresses
    auto step = [&](const int t, const int rb, const int wb, const float spf) {
        const bf16x8 hfrag =
            *reinterpret_cast<const bf16x8*>(&hbuf[rb][mb][8 * oct]);

        f32x4 acc[4];
#pragma unroll
        for (int q = 0; q < 4; ++q)
            acc[q] = __builtin_amdgcn_mfma_f32_16x16x32_bf16(wfrag[q], hfrag, zero4, 0, 0, 0);

        // head logits of step t-1 (Wo rows embedded in q=0 tile regs 2,3)
        if (rotS == ((t - 1) & 3)) {
            if (oct == 0 && m < 8)
                Sbuf[t - 1][m] = make_float2(acc[0][2], acc[0][3]);
        }

        // gate extract: reg r = hi (one cndmask each)
        const float g0 = hi ? acc[0][1] : acc[0][0];
        const float g1 = hi ? acc[1][1] : acc[1][0];
        const float g2 = hi ? acc[2][1] : acc[2][0];
        const float g3 = hi ? acc[3][1] : acc[3][0];

        // cell update; e_i=e^{-i}, e_f=e^{-f}, e_g=e^{2g}, e_o=e^{-o};
        // combined reciprocal saves one rcp.
        const float a0 = fmaf(spf, bvd[0], bv0[0]) + g0;
        const float a1 = fmaf(spf, bvd[1], bv0[1]) + g1;
        const float a2 = fmaf(spf, bvd[2], bv0[2]) + g2;
        const float a3 = fmaf(spf, bvd[3], bv0[3]) + g3;
        const float ei = fexp2(a0), ef = fexp2(a1);
        const float eg = fexp2(a2), eo = fexp2(a3);
        const float P = (1.f + ei) * (1.f + eg);
        const float Q = 1.f + ef;
        const float R = frcp(P * Q);
        const float gf  = P * R;                 // 1/(1+ef)
        const float igt = (eg - 1.f) * Q * R;    // sig(i)*tanh(g)
        c = fmaf(gf, c, igt);
        const float ec = fexp2(2.f * LOG2E * c);
        const float h  = (ec - 1.f) * frcp((1.f + eo) * (1.f + ec));
        hbuf[wb][mb][ucell] = (short)f2bf(h);
        __syncthreads();   // h_t visible to all waves of THIS WG only
    };

    // spins for pair (tb, tb+1) = bytes (tb-1, tb), prefetched a pair ahead
    unsigned sp2 = *reinterpret_cast<const unsigned short*>(&spinT[mb][0]);
    for (int tb = 1; tb < 255; tb += 2) {
        const unsigned sp2n =
            *reinterpret_cast<const unsigned short*>(&spinT[mb][tb + 1]);
        step(tb,     0, 1, (float)(sp2 & 0xFFu));
        step(tb + 1, 1, 0, (float)(sp2 >> 8));
        sp2 = sp2n;
    }
    step(255, 0, 1, (float)(sp2 & 0xFFu));   // uses spin 254

    // ---- tail: head logits of step 255 (h_255 in hbuf[1]) ----
    if (rotS == 0) {
        const bf16x8 hfrag = *reinterpret_cast<const bf16x8*>(&hbuf[1][mb][8 * oct]);
        const f32x4 hs =
            __builtin_amdgcn_mfma_f32_16x16x32_bf16(wfrag[0], hfrag, zero4, 0, 0, 0);
        if (oct == 0 && m < 8) Sbuf[255][m] = make_float2(hs[2], hs[3]);
    }
    __syncthreads();

    // ---- post phase: ELU + log-softmax + sum over t, 32 time-chunks ----
    float lp = 0.f;
    {
        const int t0 = ((w * 4 + oct) * 2 + hi) * 8;
#pragma unroll
        for (int i = 0; i < 8; ++i) {
            const int t = t0 + i;
            const float2 sv = Sbuf[t][mb];
            const int sp = spinT[mb][t];
            const float o0 = felu(sv.x + bo0);
            const float o1 = felu(sv.y + bo1);
            const float mx = fmaxf(o0, o1), mn = fminf(o0, o1);
            const float lse = mx + LN2 * flog2(1.f + fexp2(LOG2E * (mn - mx)));
            lp += (sp ? o1 : o0) - lse;
        }
    }
    lp += __shfl_xor(lp, 16, 64);   // reduce over oct
    lp += __shfl_xor(lp, 32, 64);
    lp += __shfl_xor(lp, 8, 64);    // reduce over unit-half chunk
    if (lane < 8) red[w][lane] = lp;
    __syncthreads();
    if (tid < 8) {
        float s = 0.f;
#pragma unroll
        for (int ww = 0; ww < 4; ++ww) s += red[ww][tid];
        out[b0 + tid] = 0.5f * s;
    }
    (void)hrd; (void)hstride;
}

extern "C" void kernel_launch(void* const* d_in, const int* in_sizes, int n_in,
                              void* d_out, int out_size, void* d_ws, size_t ws_size,
                              hipStream_t stream) {
    const int*   x  = (const int*)d_in[0];
    const float* Wi = (const float*)d_in[1];
    const float* Wh = (const float*)d_in[2];
    const float* bh = (const float*)d_in[3];
    const float* Wo = (const float*)d_in[4];
    const float* bo = (const float*)d_in[5];
    float* out = (float*)d_out;

    // 36 KB dynamic LDS pad: static (~20 KB) + 36 KB = ~56 KB/WG -> exactly
    // 2 WGs resident per CU; grid 512 = 2 x 256 CUs -> uniform placement.
    lstm_r12<<<dim3(Bsz / 8), dim3(256), 36000, stream>>>(x, Wi, Wh, bh, Wo, bo, out);
}